// Round 10
// baseline (4039.652 us; speedup 1.0000x reference)
//
#include <hip/hip_runtime.h>
#include <hip/hip_bf16.h>

// LightGCN K=3 propagation on MI355X.
// R8 resubmit (GPU-acquisition timeout; never ran): XCD-shard scatter +
// sort-free LDS-atomic bucket SpMM.
//   - scatter: XCD-private shard append (s_getreg HW_REG_XCC_ID) -> tail lines
//     exclusive to one XCD's L2 -> write-combining works, atomics L2-local.
//   - SpMM: sort-free. One block per 64-row bucket, LDS acc[64][64] (16KB),
//     ds_add_f32 fire-and-forget accumulate, unroll x8 gathers.
//   - scan/bucket_sort/row_start all deleted.

#define DD 64
#define BSHIFT 6
#define BROWS  (1 << BSHIFT)
#define NSH    8          // XCD shards
#define CAP    448        // entries per (xcd,bucket) shard; mean 264, +11sigma

__global__ void count_kernel(const int* __restrict__ rows, int* __restrict__ cnt, int E) {
    int i = blockIdx.x * blockDim.x + threadIdx.x;
    int stride = gridDim.x * blockDim.x;
    for (; i < E; i += stride) atomicAdd(&cnt[rows[i]], 1);
}

__global__ void factor_kernel(const int* __restrict__ cnt,
                              float* __restrict__ a_fac,
                              float* __restrict__ b_fac, int n) {
    int i = blockIdx.x * blockDim.x + threadIdx.x;
    if (i >= n) return;
    float degf = (float)(cnt[i] + 1);            // +1 self loop
    float inv_deg = 1.0f / (degf + 1e-8f);
    float deg2 = degf * inv_deg;                 // == segment_sum of inv_deg copies
    float inv_sqrt = 1.0f / sqrtf(deg2 + 1e-8f);
    a_fac[i] = inv_sqrt * inv_deg;               // matches (inv_sqrt[row] * w) grouping
    b_fac[i] = inv_sqrt;
}

// Append edge into its (xcd, bucket) shard. Entry: hi32 = w bits,
// lo32 = (r_local<<26) | c  (c < 2^17, r_local < 64).
__global__ void __launch_bounds__(256)
scatter_shard_kernel(const int* __restrict__ ei,      // [2*E] rows then cols
                     const float* __restrict__ drop,  // [E+n]
                     const float* __restrict__ a_fac,
                     const float* __restrict__ b_fac,
                     int* __restrict__ cur,           // [NSH][nbka]
                     unsigned long long* __restrict__ shard, // [NSH][nbk][CAP]
                     int E, int n, int nbk, int nbka) {
    int i = blockIdx.x * blockDim.x + threadIdx.x;
    if (i >= E + n) return;
    unsigned int xcc;
    asm volatile("s_getreg_b32 %0, hwreg(HW_REG_XCC_ID)" : "=s"(xcc));
    xcc &= (NSH - 1);
    int r, c;
    if (i < E) { r = ei[i]; c = ei[E + i]; }
    else       { r = i - E; c = r; }            // self loop
    float w = (a_fac[r] * b_fac[c]) * drop[i];
    int b = r >> BSHIFT;
    int pos = atomicAdd(&cur[xcc * nbka + b], 1);
    if (pos < CAP) {
        size_t off = ((size_t)xcc * nbk + b) * CAP + pos;
        unsigned int lo = ((unsigned int)(r & (BROWS - 1)) << 26) | (unsigned int)c;
        shard[off] = ((unsigned long long)__float_as_uint(w) << 32) | lo;
    }
}

// One block per bucket (64 rows). LDS acc[64][64] fp32; ds_add_f32 accumulate
// (fire-and-forget -> no RMW latency chain); x8 unrolled gathers for MLP.
__global__ void __launch_bounds__(256)
spmm_bucket_kernel(const int* __restrict__ cur,
                   const unsigned long long* __restrict__ shard,
                   const float* __restrict__ h_in,
                   float* __restrict__ h_out,
                   const float* __restrict__ acc_in,
                   float* __restrict__ acc_out,
                   float scale, int n, int nbk, int nbka) {
    __shared__ float accs[BROWS * DD];          // 16 KB
    int b = blockIdx.x;
    int tid = threadIdx.x;
    int lane = tid & 63;
    int wv = tid >> 6;                          // wave 0..3
    int r0 = b << BSHIFT;
    int rows = n - r0; if (rows > BROWS) rows = BROWS;

    for (int i = tid; i < BROWS * DD; i += 256) accs[i] = 0.0f;
    __syncthreads();

#define DECODE(e, rl, c, w)                                        \
    { unsigned int lo_ = (unsigned int)(e);                        \
      rl = (int)((lo_ >> 26) & (BROWS - 1));                       \
      c  = (int)(lo_ & 0x03FFFFFFu);                               \
      w  = __uint_as_float((unsigned int)((e) >> 32)); }

    for (int s = 0; s < NSH; ++s) {
        int cnt = cur[s * nbka + b]; if (cnt > CAP) cnt = CAP;
        const unsigned long long* seg = shard + ((size_t)s * nbk + b) * CAP;
        int j = wv;
        // batches of 8 entries per wave (stride 4 between waves)
        for (; j + 28 < cnt; j += 32) {
            unsigned long long e0 = seg[j];
            unsigned long long e1 = seg[j + 4];
            unsigned long long e2 = seg[j + 8];
            unsigned long long e3 = seg[j + 12];
            unsigned long long e4 = seg[j + 16];
            unsigned long long e5 = seg[j + 20];
            unsigned long long e6 = seg[j + 24];
            unsigned long long e7 = seg[j + 28];
            int r0_, c0; float w0; DECODE(e0, r0_, c0, w0);
            int r1_, c1; float w1; DECODE(e1, r1_, c1, w1);
            int r2_, c2; float w2; DECODE(e2, r2_, c2, w2);
            int r3_, c3; float w3; DECODE(e3, r3_, c3, w3);
            int r4_, c4; float w4; DECODE(e4, r4_, c4, w4);
            int r5_, c5; float w5; DECODE(e5, r5_, c5, w5);
            int r6_, c6; float w6; DECODE(e6, r6_, c6, w6);
            int r7_, c7; float w7; DECODE(e7, r7_, c7, w7);
            float v0 = h_in[c0 * DD + lane];
            float v1 = h_in[c1 * DD + lane];
            float v2 = h_in[c2 * DD + lane];
            float v3 = h_in[c3 * DD + lane];
            float v4 = h_in[c4 * DD + lane];
            float v5 = h_in[c5 * DD + lane];
            float v6 = h_in[c6 * DD + lane];
            float v7 = h_in[c7 * DD + lane];
            atomicAdd(&accs[r0_ * DD + lane], w0 * v0);
            atomicAdd(&accs[r1_ * DD + lane], w1 * v1);
            atomicAdd(&accs[r2_ * DD + lane], w2 * v2);
            atomicAdd(&accs[r3_ * DD + lane], w3 * v3);
            atomicAdd(&accs[r4_ * DD + lane], w4 * v4);
            atomicAdd(&accs[r5_ * DD + lane], w5 * v5);
            atomicAdd(&accs[r6_ * DD + lane], w6 * v6);
            atomicAdd(&accs[r7_ * DD + lane], w7 * v7);
        }
        for (; j < cnt; j += 4) {
            unsigned long long e = seg[j];
            int rl, c; float w; DECODE(e, rl, c, w);
            float v = h_in[c * DD + lane];
            atomicAdd(&accs[rl * DD + lane], w * v);
        }
    }
#undef DECODE
    __syncthreads();

    for (int r = wv; r < rows; r += 4) {
        int g = (r0 + r) * DD + lane;
        float sum = accs[(r << 6) + lane];
        h_out[g] = sum;
        acc_out[g] = (acc_in[g] + sum) * scale;
    }
}

extern "C" void kernel_launch(void* const* d_in, const int* in_sizes, int n_in,
                              void* d_out, int out_size, void* d_ws, size_t ws_size,
                              hipStream_t stream) {
    const float* x    = (const float*)d_in[0];
    const int*   ei   = (const int*)d_in[1];
    const float* drop = (const float*)d_in[2];
    float* out = (float*)d_out;

    const int N = in_sizes[0] / DD;              // 100000
    const int E = in_sizes[1] / 2;               // 3200000
    const int TOT = E + N;
    const int NBK  = (N + BROWS - 1) >> BSHIFT;  // 1563 buckets
    const int NBKA = (NBK + 15) & ~15;           // 64B-aligned cursor stride

    // workspace carve (256B aligned)
    char* p = (char*)d_ws;
    auto alloc = [&](size_t bytes) -> void* {
        void* r = (void*)p;
        p += (bytes + 255) & ~(size_t)255;
        return r;
    };
    int*   deg_cnt = (int*)  alloc((size_t)N * 4);
    float* a_fac   = (float*)alloc((size_t)N * 4);
    float* b_fac   = (float*)alloc((size_t)N * 4);
    int*   cur     = (int*)  alloc((size_t)NSH * NBKA * 4);
    unsigned long long* shard =
        (unsigned long long*)alloc((size_t)NSH * NBK * CAP * 8);   // 44.8 MB
    float* h_a     = (float*)alloc((size_t)N * DD * 4);
    float* h_b     = (float*)alloc((size_t)N * DD * 4);

    hipMemsetAsync(deg_cnt, 0, (size_t)N * 4, stream);
    hipMemsetAsync(cur, 0, (size_t)NSH * NBKA * 4, stream);

    count_kernel<<<2048, 256, 0, stream>>>(ei, deg_cnt, E);
    factor_kernel<<<(N + 255) / 256, 256, 0, stream>>>(deg_cnt, a_fac, b_fac, N);
    scatter_shard_kernel<<<(TOT + 255) / 256, 256, 0, stream>>>(
        ei, drop, a_fac, b_fac, cur, shard, E, N, NBK, NBKA);

    // hop 1: h_a = A x ; out = x + h_a
    spmm_bucket_kernel<<<NBK, 256, 0, stream>>>(cur, shard, x, h_a, x, out,
                                                1.0f, N, NBK, NBKA);
    // hop 2: h_b = A h_a ; out += h_b
    spmm_bucket_kernel<<<NBK, 256, 0, stream>>>(cur, shard, h_a, h_b, out, out,
                                                1.0f, N, NBK, NBKA);
    // hop 3: h_a = A h_b ; out = (out + h_a) * 0.25
    spmm_bucket_kernel<<<NBK, 256, 0, stream>>>(cur, shard, h_b, h_a, out, out,
                                                0.25f, N, NBK, NBKA);
}

// Round 12
// 803.307 us; speedup vs baseline: 5.0288x; 5.0288x over previous
//
#include <hip/hip_runtime.h>
#include <hip/hip_bf16.h>

// LightGCN K=3 propagation on MI355X.
// R10 resubmit (GPU-acquisition timeout; never ran): recombination.
//   - XCD-shard scatter KEPT (R8: fixed cross-XCD tail bouncing, correct).
//   - bucket-LDS SpMM REVERTED (1219us: 1563 blocks = 16x less MLP than
//     wave-per-row on a latency-bound gather).
//   - NEW csr_build: block per bucket, LDS row cursors from row_start,
//     stream shards -> row-sorted CSR. Then proven wave-per-row spmm x3.
//   - h_a aliases the dead shard buffer (keeps ws within R8's footprint).

#define DD 64
#define SCAN_BLOCK 256
#define SCAN_ITEMS 2
#define SCAN_CHUNK (SCAN_BLOCK * SCAN_ITEMS)
#define BSHIFT 6
#define BROWS  (1 << BSHIFT)
#define NSH    8          // XCD shards
#define CAP    448        // entries per (xcd,bucket) shard; mean 264, +11sigma

__global__ void count_kernel(const int* __restrict__ rows, int* __restrict__ cnt, int E) {
    int i = blockIdx.x * blockDim.x + threadIdx.x;
    int stride = gridDim.x * blockDim.x;
    for (; i < E; i += stride) atomicAdd(&cnt[rows[i]], 1);
}

__global__ void factor_kernel(const int* __restrict__ cnt,
                              float* __restrict__ a_fac,
                              float* __restrict__ b_fac, int n) {
    int i = blockIdx.x * blockDim.x + threadIdx.x;
    if (i >= n) return;
    float degf = (float)(cnt[i] + 1);            // +1 self loop
    float inv_deg = 1.0f / (degf + 1e-8f);
    float deg2 = degf * inv_deg;
    float inv_sqrt = 1.0f / sqrtf(deg2 + 1e-8f);
    a_fac[i] = inv_sqrt * inv_deg;
    b_fac[i] = inv_sqrt;
}

// ---- 3-phase device-wide exclusive scan of (cnt[i]+1) -> row_start ----
__global__ void scan_phase1(const int* __restrict__ cnt,
                            int* __restrict__ blk_sum, int n) {
    __shared__ int sh[SCAN_BLOCK];
    int b = blockIdx.x, tid = threadIdx.x;
    int base = b * SCAN_CHUNK + tid * SCAN_ITEMS;
    int s = 0;
#pragma unroll
    for (int k = 0; k < SCAN_ITEMS; ++k) {
        int i = base + k;
        if (i < n) s += cnt[i] + 1;
    }
    sh[tid] = s;
    __syncthreads();
    for (int off = SCAN_BLOCK / 2; off > 0; off >>= 1) {
        if (tid < off) sh[tid] += sh[tid + off];
        __syncthreads();
    }
    if (tid == 0) blk_sum[b] = sh[0];
}

__global__ void scan_phase2(const int* __restrict__ blk_sum,
                            int* __restrict__ blk_off, int nb) {
    __shared__ int sh[256];
    int tid = threadIdx.x;
    int m = (nb + 255) >> 8;
    int base = tid * m;
    int s = 0;
    for (int k = 0; k < m; ++k) {
        int i = base + k;
        if (i < nb) s += blk_sum[i];
    }
    sh[tid] = s;
    __syncthreads();
    for (int off = 1; off < 256; off <<= 1) {
        int v = sh[tid];
        int add = (tid >= off) ? sh[tid - off] : 0;
        __syncthreads();
        sh[tid] = v + add;
        __syncthreads();
    }
    int excl = (tid == 0) ? 0 : sh[tid - 1];
    for (int k = 0; k < m; ++k) {
        int i = base + k;
        if (i < nb) {
            blk_off[i] = excl;
            excl += blk_sum[i];
        }
    }
}

__global__ void scan_phase3(const int* __restrict__ cnt,
                            const int* __restrict__ blk_off,
                            int* __restrict__ row_start, int n) {
    __shared__ int sh[SCAN_BLOCK];
    int b = blockIdx.x, tid = threadIdx.x;
    int base = b * SCAN_CHUNK + tid * SCAN_ITEMS;
    int loc[SCAN_ITEMS];
    int s = 0;
#pragma unroll
    for (int k = 0; k < SCAN_ITEMS; ++k) {
        int i = base + k;
        int v = (i < n) ? cnt[i] + 1 : 0;
        loc[k] = s;
        s += v;
    }
    sh[tid] = s;
    __syncthreads();
    for (int off = 1; off < SCAN_BLOCK; off <<= 1) {
        int v = sh[tid];
        int add = (tid >= off) ? sh[tid - off] : 0;
        __syncthreads();
        sh[tid] = v + add;
        __syncthreads();
    }
    int thr_off = blk_off[b] + ((tid == 0) ? 0 : sh[tid - 1]);
#pragma unroll
    for (int k = 0; k < SCAN_ITEMS; ++k) {
        int i = base + k;
        if (i < n) {
            int v = thr_off + loc[k];
            row_start[i] = v;
            if (i == n - 1) row_start[n] = v + cnt[i] + 1;
        }
    }
}

// Append edge into its (xcd, bucket) shard. Entry: hi32 = w bits,
// lo32 = (r_local<<26) | c  (c < 2^17, r_local < 64).
__global__ void __launch_bounds__(256)
scatter_shard_kernel(const int* __restrict__ ei,
                     const float* __restrict__ drop,
                     const float* __restrict__ a_fac,
                     const float* __restrict__ b_fac,
                     int* __restrict__ cur,           // [NSH][nbka]
                     unsigned long long* __restrict__ shard, // [NSH][nbk][CAP]
                     int E, int n, int nbk, int nbka) {
    int i = blockIdx.x * blockDim.x + threadIdx.x;
    if (i >= E + n) return;
    unsigned int xcc;
    asm volatile("s_getreg_b32 %0, hwreg(HW_REG_XCC_ID)" : "=s"(xcc));
    xcc &= (NSH - 1);
    int r, c;
    if (i < E) { r = ei[i]; c = ei[E + i]; }
    else       { r = i - E; c = r; }            // self loop
    float w = (a_fac[r] * b_fac[c]) * drop[i];
    int b = r >> BSHIFT;
    int pos = atomicAdd(&cur[xcc * nbka + b], 1);
    if (pos < CAP) {
        size_t off = ((size_t)xcc * nbk + b) * CAP + pos;
        unsigned int lo = ((unsigned int)(r & (BROWS - 1)) << 26) | (unsigned int)c;
        shard[off] = ((unsigned long long)__float_as_uint(w) << 32) | lo;
    }
}

// Block per bucket: LDS row cursors seeded from row_start; stream the 8 shard
// segments (coalesced reads) and append each entry to its row's CSR span.
__global__ void __launch_bounds__(256)
csr_build_kernel(const int* __restrict__ shard_cur,   // [NSH][nbka]
                 const unsigned long long* __restrict__ shard,
                 const int* __restrict__ row_start,
                 unsigned long long* __restrict__ csr_ew,
                 int n, int nbk, int nbka) {
    __shared__ int cur[BROWS];
    int b = blockIdx.x, tid = threadIdx.x;
    int r0 = b << BSHIFT;
    int rows = n - r0; if (rows > BROWS) rows = BROWS;
    if (tid < rows) cur[tid] = row_start[r0 + tid];
    __syncthreads();
    for (int s = 0; s < NSH; ++s) {
        int cnt = shard_cur[s * nbka + b]; if (cnt > CAP) cnt = CAP;
        const unsigned long long* seg = shard + ((size_t)s * nbk + b) * CAP;
        for (int j = tid; j < cnt; j += 256) {
            unsigned long long v = seg[j];
            unsigned int lo = (unsigned int)v;
            int rl = (int)((lo >> 26) & (BROWS - 1));
            int pos = atomicAdd(&cur[rl], 1);
            csr_ew[pos] = (v & 0xFFFFFFFF00000000ull) |
                          (unsigned long long)(lo & 0x03FFFFFFu);
        }
    }
}

// one wave (64 lanes) per destination row; lane = feature dim.
// Edge loop unrolled x8: 8 independent gathers in flight per wave.
__global__ void __launch_bounds__(256)
spmm_kernel(const int* __restrict__ row_start,
            const unsigned long long* __restrict__ csr_ew,
            const float* __restrict__ h_in,
            float* __restrict__ h_out,
            const float* __restrict__ acc_in,
            float* __restrict__ acc_out,
            float scale, int n) {
    int wave_global = (blockIdx.x * blockDim.x + threadIdx.x) >> 6;
    int lane = threadIdx.x & 63;
    if (wave_global >= n) return;
    int beg = row_start[wave_global];
    int end = row_start[wave_global + 1];

    float s0 = 0.f, s1 = 0.f, s2 = 0.f, s3 = 0.f;
    float s4 = 0.f, s5 = 0.f, s6 = 0.f, s7 = 0.f;

    int j = beg;
    int main_end = beg + ((end - beg) & ~7);
    for (; j < main_end; j += 8) {
        unsigned long long e0 = csr_ew[j + 0];
        unsigned long long e1 = csr_ew[j + 1];
        unsigned long long e2 = csr_ew[j + 2];
        unsigned long long e3 = csr_ew[j + 3];
        unsigned long long e4 = csr_ew[j + 4];
        unsigned long long e5 = csr_ew[j + 5];
        unsigned long long e6 = csr_ew[j + 6];
        unsigned long long e7 = csr_ew[j + 7];
        int c0 = (int)(unsigned int)e0; float w0 = __uint_as_float((unsigned int)(e0 >> 32));
        int c1 = (int)(unsigned int)e1; float w1 = __uint_as_float((unsigned int)(e1 >> 32));
        int c2 = (int)(unsigned int)e2; float w2 = __uint_as_float((unsigned int)(e2 >> 32));
        int c3 = (int)(unsigned int)e3; float w3 = __uint_as_float((unsigned int)(e3 >> 32));
        int c4 = (int)(unsigned int)e4; float w4 = __uint_as_float((unsigned int)(e4 >> 32));
        int c5 = (int)(unsigned int)e5; float w5 = __uint_as_float((unsigned int)(e5 >> 32));
        int c6 = (int)(unsigned int)e6; float w6 = __uint_as_float((unsigned int)(e6 >> 32));
        int c7 = (int)(unsigned int)e7; float w7 = __uint_as_float((unsigned int)(e7 >> 32));
        float v0 = h_in[c0 * DD + lane];
        float v1 = h_in[c1 * DD + lane];
        float v2 = h_in[c2 * DD + lane];
        float v3 = h_in[c3 * DD + lane];
        float v4 = h_in[c4 * DD + lane];
        float v5 = h_in[c5 * DD + lane];
        float v6 = h_in[c6 * DD + lane];
        float v7 = h_in[c7 * DD + lane];
        s0 += w0 * v0; s1 += w1 * v1; s2 += w2 * v2; s3 += w3 * v3;
        s4 += w4 * v4; s5 += w5 * v5; s6 += w6 * v6; s7 += w7 * v7;
    }
    for (; j < end; ++j) {
        unsigned long long e = csr_ew[j];
        int c = (int)(unsigned int)e;
        float w = __uint_as_float((unsigned int)(e >> 32));
        s0 += w * h_in[c * DD + lane];
    }
    float sum = ((s0 + s1) + (s2 + s3)) + ((s4 + s5) + (s6 + s7));

    int idx = wave_global * DD + lane;
    h_out[idx] = sum;
    acc_out[idx] = (acc_in[idx] + sum) * scale;
}

extern "C" void kernel_launch(void* const* d_in, const int* in_sizes, int n_in,
                              void* d_out, int out_size, void* d_ws, size_t ws_size,
                              hipStream_t stream) {
    const float* x    = (const float*)d_in[0];
    const int*   ei   = (const int*)d_in[1];
    const float* drop = (const float*)d_in[2];
    float* out = (float*)d_out;

    const int N = in_sizes[0] / DD;              // 100000
    const int E = in_sizes[1] / 2;               // 3200000
    const int TOT = E + N;
    const int NB   = (N + SCAN_CHUNK - 1) / SCAN_CHUNK;
    const int NBK  = (N + BROWS - 1) >> BSHIFT;  // 1563 buckets
    const int NBKA = (NBK + 15) & ~15;

    // workspace carve (256B aligned)
    char* p = (char*)d_ws;
    auto alloc = [&](size_t bytes) -> void* {
        void* r = (void*)p;
        p += (bytes + 255) & ~(size_t)255;
        return r;
    };
    int*   deg_cnt   = (int*)  alloc((size_t)N * 4);
    int*   row_start = (int*)  alloc((size_t)(N + 1) * 4);
    float* a_fac     = (float*)alloc((size_t)N * 4);
    float* b_fac     = (float*)alloc((size_t)N * 4);
    int*   blk_sum   = (int*)  alloc((size_t)NB * 4);
    int*   blk_off   = (int*)  alloc((size_t)NB * 4);
    int*   shard_cur = (int*)  alloc((size_t)NSH * NBKA * 4);
    unsigned long long* shard =
        (unsigned long long*)alloc((size_t)NSH * NBK * CAP * 8);   // 44.8 MB
    unsigned long long* csr_ew =
        (unsigned long long*)alloc((size_t)TOT * 8);               // 26.4 MB
    float* h_b       = (float*)alloc((size_t)N * DD * 4);          // 25.6 MB
    float* h_a       = (float*)shard;   // alias: shard dead after csr_build

    hipMemsetAsync(deg_cnt, 0, (size_t)N * 4, stream);
    hipMemsetAsync(shard_cur, 0, (size_t)NSH * NBKA * 4, stream);

    count_kernel<<<2048, 256, 0, stream>>>(ei, deg_cnt, E);
    factor_kernel<<<(N + 255) / 256, 256, 0, stream>>>(deg_cnt, a_fac, b_fac, N);
    scan_phase1<<<NB, SCAN_BLOCK, 0, stream>>>(deg_cnt, blk_sum, N);
    scan_phase2<<<1, 256, 0, stream>>>(blk_sum, blk_off, NB);
    scan_phase3<<<NB, SCAN_BLOCK, 0, stream>>>(deg_cnt, blk_off, row_start, N);
    scatter_shard_kernel<<<(TOT + 255) / 256, 256, 0, stream>>>(
        ei, drop, a_fac, b_fac, shard_cur, shard, E, N, NBK, NBKA);
    csr_build_kernel<<<NBK, 256, 0, stream>>>(shard_cur, shard, row_start,
                                              csr_ew, N, NBK, NBKA);

    const int spmm_grid = (N + 3) / 4;   // 4 waves (rows) per 256-thread block

    // hop 1: h_a = A x ; out = x + h_a   (h_a aliases shard -- now dead)
    spmm_kernel<<<spmm_grid, 256, 0, stream>>>(row_start, csr_ew,
                                               x, h_a, x, out, 1.0f, N);
    // hop 2: h_b = A h_a ; out += h_b
    spmm_kernel<<<spmm_grid, 256, 0, stream>>>(row_start, csr_ew,
                                               h_a, h_b, out, out, 1.0f, N);
    // hop 3: h_a = A h_b ; out = (out + h_a) * 0.25
    spmm_kernel<<<spmm_grid, 256, 0, stream>>>(row_start, csr_ew,
                                               h_b, h_a, out, out, 0.25f, N);
}